// Round 3
// baseline (282.149 us; speedup 1.0000x reference)
//
#include <hip/hip_runtime.h>
#include <hip/hip_bf16.h>

// y = x @ W^T where W is dense [N,N] but strictly diagonal.
// Exact: y[t,j] = x[t,j] * W[j,j] (off-diag terms are exact 0.0f).
// Memory-bound: 128 MiB read + 128 MiB write.
//
// R2: same as R1 but with native clang ext_vector float4 (nf4) so
// __builtin_nontemporal_store accepts the pointer. 4096 blocks x 256 thr x
// 8 float4/thread; 8-load clause per thread; diag in 4 regs; NT stores.

typedef float nf4 __attribute__((ext_vector_type(4)));

constexpr int N_FEAT   = 4096;
constexpr int NVEC_ROW = N_FEAT / 4;          // 1024 nf4 per row
constexpr int VPT      = 8;                   // nf4 per thread
constexpr int BLOCK    = 256;
constexpr int VEC_PER_BLOCK = VPT * BLOCK;    // 2048 = 2 rows
// grid = 8388608 / 2048 = 4096 blocks

__global__ __launch_bounds__(BLOCK)
void diag_scale_kernel(const nf4* __restrict__ x,
                       const float* __restrict__ W,
                       nf4* __restrict__ y) {
    // Stage diagonal into LDS (16 KiB). Strided reads; L2-resident after the
    // first blocks touch the lines.
    __shared__ nf4 sdiag[NVEC_ROW];
    float* sd = reinterpret_cast<float*>(sdiag);
    for (int j = threadIdx.x; j < N_FEAT; j += BLOCK) {
        sd[j] = W[(long)j * (N_FEAT + 1)];
    }
    __syncthreads();

    const int  tid  = threadIdx.x;
    const long base = (long)blockIdx.x * VEC_PER_BLOCK;   // multiple of 1024

    // Thread's vec indices: base + j*256 + tid; diag index (j*256+tid)&1023
    // cycles with period 4 -> 4 distinct diag vectors per thread.
    nf4 dreg[4];
#pragma unroll
    for (int j = 0; j < 4; ++j) {
        dreg[j] = sdiag[(j * BLOCK + tid) & (NVEC_ROW - 1)];
    }

    // Issue all 8 global loads back-to-back (one clause, 8x MLP).
    nf4 xv[VPT];
#pragma unroll
    for (int j = 0; j < VPT; ++j) {
        xv[j] = __builtin_nontemporal_load(&x[base + j * BLOCK + tid]);
    }

#pragma unroll
    for (int j = 0; j < VPT; ++j) {
        nf4 o = xv[j] * dreg[j & 3];
        __builtin_nontemporal_store(o, &y[base + j * BLOCK + tid]);
    }
}

extern "C" void kernel_launch(void* const* d_in, const int* in_sizes, int n_in,
                              void* d_out, int out_size, void* d_ws, size_t ws_size,
                              hipStream_t stream) {
    const nf4*   x = (const nf4*)d_in[0];     // [8192, 4096] f32
    const float* W = (const float*)d_in[1];   // [4096, 4096] f32, diagonal
    nf4* y = (nf4*)d_out;                     // [8192, 4096] f32

    diag_scale_kernel<<<4096, BLOCK, 0, stream>>>(x, W, y);
}

// Round 4
// 256.876 us; speedup vs baseline: 1.0984x; 1.0984x over previous
//
#include <hip/hip_runtime.h>
#include <hip/hip_bf16.h>

// y = x @ W^T where W is dense [N,N] but strictly diagonal.
// Exact: y[t,j] = x[t,j] * W[j,j] (off-diag terms are exact 0.0f).
//
// R3: (a) compact the diagonal ONCE into contiguous d_ws (kills the ~1 GiB of
// scattered per-block L2 sector traffic the old per-block gather caused);
// (b) plain cacheable stores so y dirty-allocates into L2/LLC (256 MiB LLC
// fits x+y) and writes back off the critical path, instead of NT stores
// forcing 128 MiB synchronously to HBM inside the kernel.

typedef float nf4 __attribute__((ext_vector_type(4)));

constexpr int N_FEAT   = 4096;
constexpr int NVEC_ROW = N_FEAT / 4;          // 1024 nf4 per row
constexpr int VPT      = 8;                   // nf4 per thread
constexpr int BLOCK    = 256;
constexpr int VEC_PER_BLOCK = VPT * BLOCK;    // 2048 = 2 rows
// grid = 8388608 / 2048 = 4096 blocks

// Kernel A: compact diag(W) -> contiguous float[4096] in workspace.
__global__ __launch_bounds__(BLOCK)
void diag_compact_kernel(const float* __restrict__ W,
                         float* __restrict__ diag) {
    int j = blockIdx.x * BLOCK + threadIdx.x;   // 16 blocks x 256 = 4096
    diag[j] = W[(long)j * (N_FEAT + 1)];
}

// Kernel B: y = x * diag (row-broadcast), pure streaming.
__global__ __launch_bounds__(BLOCK)
void diag_scale_kernel(const nf4* __restrict__ x,
                       const nf4* __restrict__ diag,   // contiguous, L2-hot
                       nf4* __restrict__ y) {
    const int  tid  = threadIdx.x;
    const long base = (long)blockIdx.x * VEC_PER_BLOCK;   // multiple of 2048

    // Thread's vec indices: base + j*256 + tid; row phase cycles with period 4.
    // 4 coalesced 16B loads from the shared 16 KiB diag array (L2 broadcast).
    nf4 dreg[4];
#pragma unroll
    for (int j = 0; j < 4; ++j) {
        dreg[j] = diag[(j * BLOCK + tid) & (NVEC_ROW - 1)];
    }

    // 8-load clause, then 8 multiplies + cacheable stores.
    nf4 xv[VPT];
#pragma unroll
    for (int j = 0; j < VPT; ++j) {
        xv[j] = x[base + j * BLOCK + tid];
    }

#pragma unroll
    for (int j = 0; j < VPT; ++j) {
        y[base + j * BLOCK + tid] = xv[j] * dreg[j & 3];
    }
}

extern "C" void kernel_launch(void* const* d_in, const int* in_sizes, int n_in,
                              void* d_out, int out_size, void* d_ws, size_t ws_size,
                              hipStream_t stream) {
    const float* W = (const float*)d_in[1];   // [4096, 4096] f32, diagonal
    const nf4*   x = (const nf4*)d_in[0];     // [8192, 4096] f32
    nf4*   y    = (nf4*)d_out;                // [8192, 4096] f32
    float* diag = (float*)d_ws;               // 16 KiB scratch

    diag_compact_kernel<<<N_FEAT / BLOCK, BLOCK, 0, stream>>>(W, diag);
    diag_scale_kernel<<<4096, BLOCK, 0, stream>>>(x, (const nf4*)diag, y);
}